// Round 14
// baseline (3074.672 us; speedup 1.0000x reference)
//
#include <hip/hip_runtime.h>

#define N_EXC  512
#define NTOT   640
#define NIN    16
#define BATCH  64
#define TSTEPS 1000
#define CHUNK  160      // units per block
#define NBLKG  4        // blocks per batch sample
#define THREADS 512
#define NPT    10       // n per thread (16 ti-groups * 10 = 160)
#define RBUF_BYTES (2 * BATCH * NBLKG * CHUNK * 4)   // 327680
// ALPHA = 0.5, NOISE_SCALE = 0.01

typedef float    f32x2 __attribute__((ext_vector_type(2)));
typedef unsigned u32x4 __attribute__((ext_vector_type(4)));
typedef unsigned u32x2 __attribute__((ext_vector_type(2)));

// ---------------------------------------------------------------------------
// JAX threefry2x32, key = jax.random.key(42) -> (0, 42); partitionable bits
// ---------------------------------------------------------------------------
__device__ __forceinline__ void threefry_0_42(unsigned x0, unsigned x1,
                                              unsigned& o0, unsigned& o1) {
    const unsigned ks1 = 42u;
    const unsigned ks2 = 0x1BD11BDAu ^ 42u;
    x0 += 0u; x1 += ks1;
#define TF_RND(r) { x0 += x1; x1 = (x1 << (r)) | (x1 >> (32 - (r))); x1 ^= x0; }
    TF_RND(13) TF_RND(15) TF_RND(26) TF_RND(6)
    x0 += ks1; x1 += ks2 + 1u;
    TF_RND(17) TF_RND(29) TF_RND(16) TF_RND(24)
    x0 += ks2; x1 += 0u + 2u;
    TF_RND(13) TF_RND(15) TF_RND(26) TF_RND(6)
    x0 += 0u; x1 += ks1 + 3u;
    TF_RND(17) TF_RND(29) TF_RND(16) TF_RND(24)
    x0 += ks1; x1 += ks2 + 4u;
    TF_RND(13) TF_RND(15) TF_RND(26) TF_RND(6)
    x0 += ks2; x1 += 0u + 5u;
#undef TF_RND
    o0 = x0; o1 = x1;
}

__device__ __forceinline__ unsigned jax_bits_partitionable(unsigned idx) {
    unsigned o0, o1;
    threefry_0_42(0u, idx, o0, o1);
    return o0 ^ o1;
}

// bits -> jax.random.normal sample scaled by NOISE_SCALE*sqrt(ALPHA), f32-exact
__device__ __forceinline__ float noise_from_bits(unsigned bits) {
    float f = __uint_as_float(0x3f800000u | (bits >> 9)) - 1.0f;   // [0,1)
    float u = __fadd_rn(__fmul_rn(f, 2.0f), -0.99999994f);
    u = fmaxf(-0.99999994f, u);
    float w = -log1pf(-__fmul_rn(u, u));
    float p;
    if (w < 5.0f) {
        float ww = w - 2.5f;
        p = 2.81022636e-08f;
        p = fmaf(p, ww, 3.43273939e-07f);
        p = fmaf(p, ww, -3.5233877e-06f);
        p = fmaf(p, ww, -4.39150654e-06f);
        p = fmaf(p, ww, 0.00021858087f);
        p = fmaf(p, ww, -0.00125372503f);
        p = fmaf(p, ww, -0.00417768164f);
        p = fmaf(p, ww, 0.246640727f);
        p = fmaf(p, ww, 1.50140941f);
    } else {
        float ww = sqrtf(w) - 3.0f;
        p = -0.000200214257f;
        p = fmaf(p, ww, 0.000100950558f);
        p = fmaf(p, ww, 0.00134934322f);
        p = fmaf(p, ww, -0.00367342844f);
        p = fmaf(p, ww, 0.00573950773f);
        p = fmaf(p, ww, -0.0076224613f);
        p = fmaf(p, ww, 0.00943887047f);
        p = fmaf(p, ww, 1.00167406f);
        p = fmaf(p, ww, 2.83297682f);
    }
    float z = 1.41421354f * (p * u);
    return (0.01f * 0.70710677f) * z;
}

// round-to-nearest-even bf16 (low 16 bits of result)
__device__ __forceinline__ unsigned rne_bf16(float f) {
    unsigned u = __float_as_uint(f);
    return (u + 0x7FFFu + ((u >> 16) & 1u)) >> 16;
}

// dale-transformed weights for units (n0,n1) at input k, bf16-packed lo|hi<<16
__device__ __forceinline__ unsigned packw2(const float* __restrict__ W,
                                           int n0, int n1, int k, float sg) {
    float lo = fabsf(W[(size_t)n0 * NTOT + k]) * sg; if (n0 == k) lo = 0.f;
    float hi = fabsf(W[(size_t)n1 * NTOT + k]) * sg; if (n1 == k) hi = 0.f;
    return rne_bf16(lo) | (rne_bf16(hi) << 16);
}

// packed u32 -> f32x2 (bf16 lo/hi widened exactly)
__device__ __forceinline__ f32x2 uf2(unsigned u) {
    u32x2 t = {u << 16, u & 0xFFFF0000u};
    return __builtin_bit_cast(f32x2, t);
}

// ---------------------------------------------------------------------------
// Persistent kernel: 256 blocks = 4 chunk-blocks x 64 batches, 512 threads.
// Proven (r11-r13): LDS>80KB -> 1 WG/CU -> no spill; lane-major LDS weights;
// self-flagging tagged-data sync (no flag array, no acquire storms).
// r14: critical-path surgery.
//  - k-slots remapped to 4 chunk-slots (slot j <-> chunk (g+j)&3, 5 k each,
//    STATIC register names): slot 0 = own chunk runs between barrier-1 and
//    barrier-2, overlapping the pollers' L2 round-trip.
//  - rates_b HBM store deferred past barrier-2 (drains under slot-1..3 GEMV,
//    not at a bare barrier: __syncthreads implies s_waitcnt vmcnt(0)).
//  - next-step u prefetched after barrier-2 into parity buffer.
// ---------------------------------------------------------------------------
__global__ __launch_bounds__(THREADS)
void eirnn_sync(const float* __restrict__ inputs, const float* __restrict__ Wraw,
                const float* __restrict__ W_in, const float* __restrict__ W_out,
                const float* __restrict__ b_out, float* __restrict__ rates_out,
                float* __restrict__ outs_out, unsigned* __restrict__ rbuf) {
    const int b   = blockIdx.x & 63;
    const int g   = blockIdx.x >> 6;       // 0..3
    const int tid = threadIdx.x;
    const int ti  = tid & 15;              // n-group (0..15)
    const int tj  = tid >> 4;              // k-group (0..31), 5 k per chunk
    const int wv  = tid >> 6;              // wave (0..7)
    const int nbase = g * CHUNK;
    const int nloc  = nbase + ti * NPT;    // first owned n (global id)

    __shared__ __align__(16) float r_all[2][NTOT];
    __shared__ __align__(8)  float part[8 * CHUNK];   // [wave][160]
    __shared__ float win_s[CHUNK * 17];
    __shared__ float wo_s[2 * N_EXC];
    __shared__ float u_s[2][NIN];
    __shared__ float red0[8], red1[8];
    __shared__ float bo_s[2];
    // LDS-resident packed weights, LANE-MAJOR [slot][tid]; slot = j*2+(kk-3)
    __shared__ u32x4    w4_lds[8 * THREADS];   // 64 KB
    __shared__ unsigned w1_lds[8 * THREADS];   // 16 KB

    // ---- named packed-bf16 weight registers: 4 chunk-slots x 3 k x 5 u32 --
#define DECLSLOT(J) u32x4 wA##J##0, wA##J##1, wA##J##2; \
                    unsigned wB##J##0, wB##J##1, wB##J##2;
    DECLSLOT(0) DECLSLOT(1) DECLSLOT(2) DECLSLOT(3)
#undef DECLSLOT

#define MAKE4(K_, SG_) (u32x4){packw2(Wraw, nloc + 0, nloc + 1, K_, SG_),   \
                               packw2(Wraw, nloc + 2, nloc + 3, K_, SG_),   \
                               packw2(Wraw, nloc + 4, nloc + 5, K_, SG_),   \
                               packw2(Wraw, nloc + 6, nloc + 7, K_, SG_)}
#define LOADSLOT(J) {                                                       \
        const int cb_ = ((g + (J)) & 3) * CHUNK + tj * 5;                   \
        { const int k_ = cb_ + 0; const float sg_ = (k_ < N_EXC) ? 1.f : -1.f; \
          wA##J##0 = MAKE4(k_, sg_);                                        \
          wB##J##0 = packw2(Wraw, nloc + 8, nloc + 9, k_, sg_); }           \
        { const int k_ = cb_ + 1; const float sg_ = (k_ < N_EXC) ? 1.f : -1.f; \
          wA##J##1 = MAKE4(k_, sg_);                                        \
          wB##J##1 = packw2(Wraw, nloc + 8, nloc + 9, k_, sg_); }           \
        { const int k_ = cb_ + 2; const float sg_ = (k_ < N_EXC) ? 1.f : -1.f; \
          wA##J##2 = MAKE4(k_, sg_);                                        \
          wB##J##2 = packw2(Wraw, nloc + 8, nloc + 9, k_, sg_); }           \
        { const int k_ = cb_ + 3; const float sg_ = (k_ < N_EXC) ? 1.f : -1.f; \
          w4_lds[((J) * 2 + 0) * THREADS + tid] = MAKE4(k_, sg_);           \
          w1_lds[((J) * 2 + 0) * THREADS + tid] =                           \
              packw2(Wraw, nloc + 8, nloc + 9, k_, sg_); }                  \
        { const int k_ = cb_ + 4; const float sg_ = (k_ < N_EXC) ? 1.f : -1.f; \
          w4_lds[((J) * 2 + 1) * THREADS + tid] = MAKE4(k_, sg_);           \
          w1_lds[((J) * 2 + 1) * THREADS + tid] =                           \
              packw2(Wraw, nloc + 8, nloc + 9, k_, sg_); }                  \
    }
    LOADSLOT(0) LOADSLOT(1) LOADSLOT(2) LOADSLOT(3)
#undef LOADSLOT
#undef MAKE4

    // W_in chunk -> LDS (padded stride 17); W_out/b_out -> LDS
    for (int i = tid; i < CHUNK * NIN; i += THREADS) {
        int o = i >> 4, j = i & 15;
        win_s[o * 17 + j] = W_in[(nbase + o) * NIN + j];
    }
    for (int i = tid; i < 2 * N_EXC; i += THREADS) wo_s[i] = W_out[i];
    if (tid < 2) bo_s[tid] = b_out[tid];

    const float* inp_b = inputs    + (size_t)b * TSTEPS * NIN;
    float* rates_b     = rates_out + (size_t)b * TSTEPS * NTOT;
    float* outs_b      = outs_out  + (size_t)b * TSTEPS * 2;

    // poller role: threads [32, 512) each own one remote word
    const int pidx = tid - 32;             // 0..479 when tid>=32
    const int pp   = pidx / CHUNK;         // 0..2
    const int pgg  = pp + (pp >= g ? 1 : 0);
    const int po   = pidx - pp * CHUNK;

    // prologue: u for t=0
    if (tid >= THREADS - NIN)
        u_s[0][tid - (THREADS - NIN)] = inp_b[tid - (THREADS - NIN)];

    float x = 0.0f;   // owner state for tid < CHUNK
    __syncthreads();  // LDS weights/win_s/wo_s/bo_s/u_s[0] ready

    for (int t = 0; t < TSTEPS; ++t) {
        const int buf = t & 1;
        const unsigned tagv = (unsigned)(t & 3);
        unsigned* rb_base = rbuf + (size_t)(buf * BATCH + b) * (NBLKG * CHUNK);
        const float* ra = r_all[buf];

        // ---- phase A: owners publish tagged rate (L2 only; HBM store later)
        float r_exact = 0.0f;
        if (tid < CHUNK) {
            r_exact = fmaxf(x, 0.0f) + log1pf(expf(-fabsf(x)));
            unsigned rbits = (__float_as_uint(r_exact) & ~3u) | tagv;
            r_all[buf][nbase + tid] = __uint_as_float(rbits);
            __hip_atomic_store(rb_base + g * CHUNK + tid, rbits,
                               __ATOMIC_RELAXED, __HIP_MEMORY_SCOPE_AGENT);
        }
        __syncthreads();   // b1: local r segment ready (drains only L2 publish)

        // speculative first poll load (issued before local compute)
        const unsigned* psrc = rb_base + pgg * CHUNK + po;
        unsigned wspec = 0u;
        if (tid >= 32)
            wspec = __hip_atomic_load(psrc, __ATOMIC_RELAXED,
                                      __HIP_MEMORY_SCOPE_AGENT);

        // accumulators live across barriers
        f32x2 acc0 = {0.f, 0.f}, acc1 = {0.f, 0.f}, acc2 = {0.f, 0.f};
        f32x2 acc3 = {0.f, 0.f}, acc4 = {0.f, 0.f};
#define FMA5(WA, WB, RK) { acc0 += uf2((WA).x) * (RK);                      \
                           acc1 += uf2((WA).y) * (RK);                      \
                           acc2 += uf2((WA).z) * (RK);                      \
                           acc3 += uf2((WA).w) * (RK);                      \
                           acc4 += uf2(WB)     * (RK); }
#define GEMV_SLOT(J) {                                                      \
        const float* rc_ = ra + (((g + (J)) & 3) * CHUNK + tj * 5);         \
        const float r0_ = rc_[0], r1_ = rc_[1], r2_ = rc_[2];               \
        const float r3_ = rc_[3], r4_ = rc_[4];                             \
        FMA5(wA##J##0, wB##J##0, r0_)                                       \
        FMA5(wA##J##1, wB##J##1, r1_)                                       \
        FMA5(wA##J##2, wB##J##2, r2_)                                       \
        { u32x4 wa_ = w4_lds[((J) * 2 + 0) * THREADS + tid];                \
          unsigned wb_ = w1_lds[((J) * 2 + 0) * THREADS + tid];             \
          FMA5(wa_, wb_, r3_) }                                             \
        { u32x4 wa_ = w4_lds[((J) * 2 + 1) * THREADS + tid];                \
          unsigned wb_ = w1_lds[((J) * 2 + 1) * THREADS + tid];             \
          FMA5(wa_, wb_, r4_) }                                             \
    }
        // ---- own-chunk GEMV overlaps the pollers' L2 round-trip ------------
        GEMV_SLOT(0)

        if (tid >= 32) {                   // pollers: data IS the flag
            unsigned w = wspec;
            while (((w & 3u) != tagv) || ((int)w <= 0x00800000)) {
                w = __hip_atomic_load(psrc, __ATOMIC_RELAXED,
                                      __HIP_MEMORY_SCOPE_AGENT);
            }
            r_all[buf][pgg * CHUNK + po] = __uint_as_float(w);
        }
        __syncthreads();   // b2: full r_all ready

        // deferred HBM work: drains under the remaining GEMV, not at a barrier
        if (tid < CHUNK) rates_b[t * NTOT + nbase + tid] = r_exact;
        if (tid >= THREADS - NIN && t + 1 < TSTEPS)
            u_s[(t + 1) & 1][tid - (THREADS - NIN)] =
                inp_b[(t + 1) * NIN + (tid - (THREADS - NIN))];

        // ---- remaining 3 chunks ------------------------------------------
        GEMV_SLOT(1) GEMV_SLOT(2) GEMV_SLOT(3)
#undef GEMV_SLOT
#undef FMA5
        // reduce over the 4 tj-groups inside this wave (lane bits 4,5)
#define WRED(S) { S.x += __shfl_xor(S.x, 16); S.x += __shfl_xor(S.x, 32);   \
                  S.y += __shfl_xor(S.y, 16); S.y += __shfl_xor(S.y, 32); }
        WRED(acc0) WRED(acc1) WRED(acc2) WRED(acc3) WRED(acc4)
#undef WRED
        if ((tid & 63) < 16) {             // lane == ti
            float* pq = &part[wv * CHUNK + (tid & 15) * NPT];
            *(f32x2*)(pq + 0) = acc0;
            *(f32x2*)(pq + 2) = acc1;
            *(f32x2*)(pq + 4) = acc2;
            *(f32x2*)(pq + 6) = acc3;
            *(f32x2*)(pq + 8) = acc4;
        }
        // readout partials on g==0 (r_all[buf] is complete r_t)
        if (g == 0) {
            float rr = r_all[buf][tid];
            float p0 = rr * wo_s[tid], p1 = rr * wo_s[N_EXC + tid];
#pragma unroll
            for (int off = 32; off; off >>= 1) {
                p0 += __shfl_down(p0, off);
                p1 += __shfl_down(p1, off);
            }
            if ((tid & 63) == 0) { red0[wv] = p0; red1[wv] = p1; }
        }
        __syncthreads();   // b3: part/red ready

        // ---- phase D: owner state update (no trailing barrier) -------------
        if (tid < CHUNK) {
            float rec = 0.0f;
#pragma unroll
            for (int j = 0; j < 8; ++j) rec += part[j * CHUNK + tid];
            float ext = 0.0f;
#pragma unroll
            for (int j = 0; j < NIN; ++j)
                ext = fmaf(win_s[tid * 17 + j], u_s[buf][j], ext);
            unsigned idx = (unsigned)(t * (BATCH * NTOT) + b * NTOT + (nbase + tid));
            float eps = noise_from_bits(jax_bits_partitionable(idx));
            x = (0.5f * x + 0.5f * (rec + ext)) + eps;
        }
        if (g == 0 && tid == 0) {
            float y0 = bo_s[0], y1 = bo_s[1];
#pragma unroll
            for (int k = 0; k < 8; ++k) { y0 += red0[k]; y1 += red1[k]; }
            outs_b[t * 2 + 0] = y0;
            outs_b[t * 2 + 1] = y1;
        }
        // next iteration's writes are fenced by next barriers (parity buffers)
    }
}

// ---------------------------------------------------------------------------
extern "C" void kernel_launch(void* const* d_in, const int* in_sizes, int n_in,
                              void* d_out, int out_size, void* d_ws, size_t ws_size,
                              hipStream_t stream) {
    const float* inputs = (const float*)d_in[0];   // [64,1000,16]
    const float* Wraw   = (const float*)d_in[1];   // [640,640]
    const float* W_in   = (const float*)d_in[2];   // [640,16]
    const float* W_out  = (const float*)d_in[3];   // [2,512]
    const float* b_out  = (const float*)d_in[4];   // [2]

    float* out   = (float*)d_out;
    float* rates = out;                                    // [64,1000,640]
    float* outs  = out + (size_t)BATCH * TSTEPS * NTOT;    // [64,1000,2]

    unsigned* rbuf = (unsigned*)d_ws;   // [2][64][4][160] u32 (tagged rates)

    // sentinel-fill each call (0xAAAAAAAA: negative & tag=2 -> rejected at
    // t=0 (tag 0) and t=1 (tag 1); in-graph so every replay is identical)
    hipMemsetAsync(d_ws, 0xAA, RBUF_BYTES, stream);
    eirnn_sync<<<dim3(NBLKG * BATCH), dim3(THREADS), 0, stream>>>(
        inputs, Wraw, W_in, W_out, b_out, rates, outs, rbuf);
}